// Round 3
// baseline (162.078 us; speedup 1.0000x reference)
//
#include <hip/hip_runtime.h>
#include <hip/hip_bf16.h>

#define SEQ 394
#define EMB 300
#define DEPTH 256

typedef __attribute__((ext_vector_type(8))) short short8;
typedef __attribute__((ext_vector_type(4))) float f32x4;

__device__ __forceinline__ unsigned short f2b(float f) {
    unsigned u = __float_as_uint(f);
    u += 0x7FFFu + ((u >> 16) & 1u);   // RNE to bf16
    return (unsigned short)(u >> 16);
}

__device__ __forceinline__ void gload_lds16(const void* g, void* l) {
    __builtin_amdgcn_global_load_lds(
        (const __attribute__((address_space(1))) void*)g,
        (__attribute__((address_space(3))) void*)l, 16, 0, 0);
}

// ---------------- pack kernels ----------------

__global__ __launch_bounds__(256)
void pack_x_kernel(const float* __restrict__ x,
                   unsigned short* __restrict__ xp,
                   unsigned short* __restrict__ xsh)
{
    const long TOT = (long)64 * SEQ * EMB;           // 7,564,800
    long i4 = ((long)blockIdx.x * 256 + threadIdx.x) * 4;
    if (i4 >= TOT) return;
    float4 v = *(const float4*)(x + i4);
    ushort4 u = make_ushort4(f2b(v.x), f2b(v.y), f2b(v.z), f2b(v.w));
    *(ushort4*)(xp + i4) = u;
    if (i4 >= 4) *(ushort4*)(xsh + i4 - 4) = u;      // xsh[e-4] = x[e]
}

__global__ __launch_bounds__(256)
void pack_w_kernel(const float* __restrict__ W1, const float* __restrict__ W2,
                   const float* __restrict__ W3, unsigned short* __restrict__ wp)
{
    const int br = blockIdx.z;
    const int K  = 900 + br * 300;
    const int Kp = (br == 0) ? 928 : (br == 1) ? 1216 : 1504;
    const float* Wg = (br == 0) ? W1 : (br == 1) ? W2 : W3;
    unsigned short* dst = wp + ((br == 0) ? 0 : (br == 1) ? 256 * 928 : 256 * (928 + 1216));
    int idx = blockIdx.x * 256 + threadIdx.x;
    int kq = Kp >> 2;
    int tot = 256 * kq;
    if (idx >= tot) return;
    int d  = idx / kq;
    int k4 = (idx - d * kq) * 4;
    ushort4 u;
    if (k4 < K) {
        float4 v = *(const float4*)(Wg + (long)d * K + k4);
        u = make_ushort4(f2b(v.x), f2b(v.y), f2b(v.z), f2b(v.w));
    } else {
        u = make_ushort4(0, 0, 0, 0);
    }
    *(ushort4*)(dst + (long)d * Kp + k4) = u;
}

// ---- main GEMM: counted-vmcnt 4-buffer pipeline, T2 LDS swizzle, T1 XCD swizzle ----

__global__ __launch_bounds__(256, 2)
void gemm_kernel(const unsigned short* __restrict__ xp,
                 const unsigned short* __restrict__ xsh,
                 const unsigned short* __restrict__ wp,
                 const float* __restrict__ b1, const float* __restrict__ b2,
                 const float* __restrict__ b3,
                 float* __restrict__ out)
{
    // T1: bijective chunked XCD swizzle (m204), NWG = 1172, linear = gx*2 + mt
    const int did = blockIdx.x;                  // dispatch order, round-robin over 8 XCDs
    const int xcd = did & 7, idx = did >> 3;
    const int q = 146, r = 4;                    // 1172 = 8*146 + 4
    const int swz = (xcd < r ? xcd * (q + 1) : r * (q + 1) + (xcd - r) * q) + idx;
    const int gx = swz >> 1;                     // column tile 0..585
    const int mt = swz & 1;                      // m tile

    int br, nt;
    if (gx < 196)      { br = 0; nt = gx; }
    else if (gx < 391) { br = 1; nt = gx - 196; }
    else               { br = 2; nt = gx - 391; }
    const int Kp   = (br == 0) ? 928 : (br == 1) ? 1216 : 1504;
    const int Nw   = 391 - br;
    const int NTOT = Nw * 64;
    const unsigned short* Wp = wp + ((br == 0) ? 0 : (br == 1) ? 256 * 928 : 256 * (928 + 1216));
    const float* bg = (br == 0) ? b1 : (br == 1) ? b2 : b3;
    const int dbase = mt * 128;
    const int n0    = nt * 128;
    const int nch   = Kp >> 5;                   // 29 / 38 / 47

    __shared__ unsigned short Wl[4][128][32];
    __shared__ unsigned short Xl[4][128][32];

    const int tid  = threadIdx.x;
    const int lane = tid & 63;
    const int wid  = tid >> 6;
    const int rsub = lane >> 2;                  // staging row within 16-row group
    // T2 source pre-swizzle: lane's linear LDS slot (lane&3) must hold logical
    // granule qg = (lane&3) ^ ((rsub>>1)&3)
    const int qg8  = ((lane & 3) ^ ((rsub >> 1) & 3)) * 8;
    const int wr = wid >> 1, wc = wid & 1;
    const int lr = lane & 15, lg = lane >> 4;
    // T2 read swizzle: logical granule lg of row (..+lr) lives at slot lg ^ ((lr>>1)&3)
    const int rcol = ((lg ^ ((lr >> 1) & 3)) * 8);

    // per-thread global staging addresses (advance 32 elems/chunk)
    const unsigned short* gA[2];
    const unsigned short* gX[2];
#pragma unroll
    for (int j = 0; j < 2; ++j) {
        int rowA = j * 64 + wid * 16 + rsub;
        gA[j] = Wp + (long)(dbase + rowA) * Kp + qg8;
        int nX = n0 + j * 64 + wid * 16 + rsub;
        if (nX < NTOT) {
            int b = nX / Nw;
            int i = nX - b * Nw;
            int m = b * SEQ + i;
            const unsigned short* base = (m & 1) ? xsh : xp;
            long eoff = (long)m * EMB - ((m & 1) ? 4 : 0) + qg8;
            gX[j] = base + eoff;
        } else {
            gX[j] = xp + qg8;                    // harmless; masked in epilogue
        }
    }

    f32x4 acc[4][4];
#pragma unroll
    for (int i = 0; i < 4; ++i)
#pragma unroll
        for (int j = 0; j < 4; ++j)
            acc[i][j] = (f32x4)0.0f;

    // prologue: stage chunks 0,1,2 into bufs 0,1,2 (12 loads in flight)
#pragma unroll
    for (int p = 0; p < 3; ++p) {
        const int k0 = p << 5;
#pragma unroll
        for (int j = 0; j < 2; ++j) {
            gload_lds16(gA[j] + k0, &Wl[p][j * 64 + wid * 16][0]);
            gload_lds16(gX[j] + k0, &Xl[p][j * 64 + wid * 16][0]);
        }
    }

    for (int c = 0; c < nch; ++c) {
        // counted wait: chunk c complete, chunks c+1/c+2 remain in flight
        if (c + 2 < nch)      asm volatile("s_waitcnt vmcnt(8)" ::: "memory");
        else if (c + 1 < nch) asm volatile("s_waitcnt vmcnt(4)" ::: "memory");
        else                  asm volatile("s_waitcnt vmcnt(0)" ::: "memory");
        __builtin_amdgcn_sched_barrier(0);
        __builtin_amdgcn_s_barrier();            // all waves: chunk c ready; prior reads done
        __builtin_amdgcn_sched_barrier(0);

        if (c + 3 < nch) {                       // refill into buf being retired
            const int bnext = (c + 3) & 3;
            const int k0 = (c + 3) << 5;
#pragma unroll
            for (int j = 0; j < 2; ++j) {
                gload_lds16(gA[j] + k0, &Wl[bnext][j * 64 + wid * 16][0]);
                gload_lds16(gX[j] + k0, &Xl[bnext][j * 64 + wid * 16][0]);
            }
        }

        const int cur = c & 3;
        short8 af[4], bx[4];
#pragma unroll
        for (int mi = 0; mi < 4; ++mi)
            af[mi] = *(const short8*)&Wl[cur][wr * 64 + mi * 16 + lr][rcol];
#pragma unroll
        for (int ni = 0; ni < 4; ++ni)
            bx[ni] = *(const short8*)&Xl[cur][wc * 64 + ni * 16 + lr][rcol];
#pragma unroll
        for (int mi = 0; mi < 4; ++mi)
#pragma unroll
            for (int ni = 0; ni < 4; ++ni)
                acc[mi][ni] = __builtin_amdgcn_mfma_f32_16x16x32_bf16(af[mi], bx[ni], acc[mi][ni], 0, 0, 0);
        __builtin_amdgcn_sched_barrier(0);       // nothing crosses into next iter's wait
    }

    // epilogue: bias+relu+mask, segmented (<=2 batches per 64-window span)
    const int obr = br * 256;
    const int nb  = n0 + wc * 64;
    const int B0  = nb / Nw;
    const bool cross = (nb + 63) >= (B0 + 1) * Nw;
#pragma unroll
    for (int mi = 0; mi < 4; ++mi) {
#pragma unroll
        for (int rI = 0; rI < 4; ++rI) {
            const int d = dbase + wr * 64 + mi * 16 + lg * 4 + rI;
            const float bv = bg[d];
            float vlo = 0.f, vhi = 0.f;
#pragma unroll
            for (int ni = 0; ni < 4; ++ni) {
                int n = nb + ni * 16 + lr;
                float v = fmaxf(acc[mi][ni][rI] + bv, 0.f);
                if (n >= NTOT) v = 0.f;
                bool hi = (n - B0 * Nw) >= Nw;
                vlo = hi ? vlo : fmaxf(vlo, v);
                vhi = hi ? fmaxf(vhi, v) : vhi;
            }
#pragma unroll
            for (int off = 1; off < 16; off <<= 1) {
                vlo = fmaxf(vlo, __shfl_xor(vlo, off));
                vhi = fmaxf(vhi, __shfl_xor(vhi, off));
            }
            if (lr == 0 && B0 < 64)
                atomicMax((int*)(out + (long)B0 * 768 + obr + d), __float_as_int(vlo));
            if (lr == 0 && cross && (B0 + 1) < 64)
                atomicMax((int*)(out + (long)(B0 + 1) * 768 + obr + d), __float_as_int(vhi));
        }
    }
}

// ---------------- fallback if ws too small ----------------

__device__ __forceinline__ void load_chunk(const float* __restrict__ Wg,
                                           const float* __restrict__ xb,
                                           int K, int dbase, int i0, int k0, int tid,
                                           float4 wv[4], float4 xv[4])
{
#pragma unroll
    for (int i = 0; i < 4; ++i) {
        int fi  = tid + (i << 8);
        int row = fi >> 3;
        int c4  = (fi & 7) << 2;
        int col = k0 + c4;
        if (col < K)
            wv[i] = *(const float4*)(Wg + (long)(dbase + row) * K + col);
        else
            wv[i] = make_float4(0.f, 0.f, 0.f, 0.f);
        int off = (i0 + row) * EMB + col;
        int lim = SEQ * EMB - 4;
        if (off > lim) off = lim;
        xv[i] = *(const float4*)(xb + off);
    }
}

__device__ __forceinline__ void write_chunk(unsigned short (*Wb)[40],
                                            unsigned short (*Xb)[40],
                                            int tid, const float4 wv[4], const float4 xv[4])
{
#pragma unroll
    for (int i = 0; i < 4; ++i) {
        int fi  = tid + (i << 8);
        int row = fi >> 3;
        int c4  = (fi & 7) << 2;
        *(ushort4*)&Wb[row][c4] = make_ushort4(f2b(wv[i].x), f2b(wv[i].y), f2b(wv[i].z), f2b(wv[i].w));
        *(ushort4*)&Xb[row][c4] = make_ushort4(f2b(xv[i].x), f2b(xv[i].y), f2b(xv[i].z), f2b(xv[i].w));
    }
}

__global__ __launch_bounds__(256, 2)
void convmax_fallback(const float* __restrict__ x,
                      const float* __restrict__ W1, const float* __restrict__ W2,
                      const float* __restrict__ W3,
                      const float* __restrict__ b1, const float* __restrict__ b2,
                      const float* __restrict__ b3,
                      float* __restrict__ out)
{
    const int br = blockIdx.z;
    const int K  = (br == 0) ? 900 : (br == 1) ? 1200 : 1500;
    const int Nw = SEQ - 3 - br;
    const float* Wg = (br == 0) ? W1 : (br == 1) ? W2 : W3;
    const float* bg = (br == 0) ? b1 : (br == 1) ? b2 : b3;
    const int b  = blockIdx.x;
    const int mt = blockIdx.y >> 2;
    const int nt = blockIdx.y & 3;
    const int dbase = mt * 128;
    const int i0    = nt * 128;
    const float* xb = x + b * (SEQ * EMB);
    const int nch = (K + 31) >> 5;

    __shared__ unsigned short Wl[2][128][40];
    __shared__ unsigned short Xl[2][128][40];

    const int tid  = threadIdx.x;
    const int lane = tid & 63;
    const int wid  = tid >> 6;
    const int wr = wid >> 1, wc = wid & 1;
    const int lr = lane & 15, lg = lane >> 4;

    f32x4 acc[4][4];
#pragma unroll
    for (int i = 0; i < 4; ++i)
#pragma unroll
        for (int j = 0; j < 4; ++j)
            acc[i][j] = (f32x4)0.0f;

    {
        float4 wv[4], xv[4];
        load_chunk(Wg, xb, K, dbase, i0, 0, tid, wv, xv);
        write_chunk(Wl[0], Xl[0], tid, wv, xv);
    }
    __syncthreads();

    for (int c = 0; c < nch; ++c) {
        const int cur = c & 1;
        float4 wv[4], xv[4];
        const bool pf = (c + 1 < nch);
        if (pf) load_chunk(Wg, xb, K, dbase, i0, (c + 1) << 5, tid, wv, xv);

        short8 af[4], bfr[4];
#pragma unroll
        for (int mi = 0; mi < 4; ++mi)
            af[mi] = *(const short8*)&Wl[cur][wr * 64 + mi * 16 + lr][lg * 8];
#pragma unroll
        for (int ni = 0; ni < 4; ++ni)
            bfr[ni] = *(const short8*)&Xl[cur][wc * 64 + ni * 16 + lr][lg * 8];
#pragma unroll
        for (int mi = 0; mi < 4; ++mi)
#pragma unroll
            for (int ni = 0; ni < 4; ++ni)
                acc[mi][ni] = __builtin_amdgcn_mfma_f32_16x16x32_bf16(af[mi], bfr[ni], acc[mi][ni], 0, 0, 0);

        if (pf) write_chunk(Wl[cur ^ 1], Xl[cur ^ 1], tid, wv, xv);
        __syncthreads();
    }

    const int ob = b * 768 + br * 256;
#pragma unroll
    for (int mi = 0; mi < 4; ++mi) {
#pragma unroll
        for (int rI = 0; rI < 4; ++rI) {
            const int d = dbase + wr * 64 + mi * 16 + lg * 4 + rI;
            const float bv = bg[d];
            float m = 0.f;
#pragma unroll
            for (int ni = 0; ni < 4; ++ni) {
                int win = i0 + wc * 64 + ni * 16 + lr;
                float v = acc[mi][ni][rI] + bv;
                v = fmaxf(v, 0.f);
                if (win >= Nw) v = 0.f;
                m = fmaxf(m, v);
            }
#pragma unroll
            for (int off = 1; off < 16; off <<= 1)
                m = fmaxf(m, __shfl_xor(m, off));
            if (lr == 0)
                atomicMax((int*)(out + ob + d), __float_as_int(m));
        }
    }
}

// ---------------- launch ----------------

extern "C" void kernel_launch(void* const* d_in, const int* in_sizes, int n_in,
                              void* d_out, int out_size, void* d_ws, size_t ws_size,
                              hipStream_t stream) {
    const float* x  = (const float*)d_in[0];
    const float* W1 = (const float*)d_in[1];
    const float* W2 = (const float*)d_in[2];
    const float* W3 = (const float*)d_in[3];
    const float* b1 = (const float*)d_in[4];
    const float* b2 = (const float*)d_in[5];
    const float* b3 = (const float*)d_in[6];
    float* out = (float*)d_out;

    hipMemsetAsync(d_out, 0, (size_t)out_size * sizeof(float), stream);

    const long XTOT = (long)64 * SEQ * EMB;                  // 7,564,800 elements
    const size_t need = (size_t)(2 * XTOT + 256L * (928 + 1216 + 1504)) * 2;  // ~32.1 MB

    if (ws_size >= need) {
        unsigned short* xp  = (unsigned short*)d_ws;
        unsigned short* xsh = xp + XTOT;
        unsigned short* wp  = xsh + XTOT;

        int nblk_x = (int)((XTOT / 4 + 255) / 256);          // 7388
        pack_x_kernel<<<nblk_x, 256, 0, stream>>>(x, xp, xsh);
        pack_w_kernel<<<dim3(376, 1, 3), 256, 0, stream>>>(W1, W2, W3, wp);
        gemm_kernel<<<dim3(1172, 1, 1), 256, 0, stream>>>(xp, xsh, wp, b1, b2, b3, out);
    } else {
        dim3 grid(64, 8, 3);
        convmax_fallback<<<grid, 256, 0, stream>>>(x, W1, W2, W3, b1, b2, b3, out);
    }
}

// Round 4
// 92.520 us; speedup vs baseline: 1.7518x; 1.7518x over previous
//
#include <hip/hip_runtime.h>
#include <hip/hip_bf16.h>

#define SEQ 394
#define EMB 300

typedef __attribute__((ext_vector_type(8))) short short8;
typedef __attribute__((ext_vector_type(4))) short short4v;
typedef __attribute__((ext_vector_type(4))) float f32x4;

#define NCH0 29
#define NCH1 67    // cumulative: br1 ends here
#define NCHT 114   // total K-chunks of 32 across the 3 branches (928+1216+1504)/32
#define XELEM 34816        // resident X elems (covers w_local<=111, k<1504, +pad)
#define XGRAN 4352         // XELEM/8
#define WBUF_ELEM 8192     // one W chunk: 256 filters x 32 k = 16KB

__device__ __forceinline__ unsigned short f2b(float f) {
    unsigned u = __float_as_uint(f);
    u += 0x7FFFu + ((u >> 16) & 1u);   // RNE to bf16
    return (unsigned short)(u >> 16);
}

__device__ __forceinline__ void gload_lds16(const void* g, void* l) {
    __builtin_amdgcn_global_load_lds(
        (const __attribute__((address_space(1))) void*)g,
        (__attribute__((address_space(3))) void*)l, 16, 0, 0);
}

// ---------------- pack kernels ----------------

// x fp32 -> bf16 flat copy (single copy; all resident-fill starts are 16B-aligned)
__global__ __launch_bounds__(256)
void pack_x_kernel(const float* __restrict__ x, unsigned short* __restrict__ xp)
{
    const long TOT = (long)64 * SEQ * EMB;           // 7,564,800
    long i4 = ((long)blockIdx.x * 256 + threadIdx.x) * 4;
    if (i4 >= TOT) return;
    float4 v = *(const float4*)(x + i4);
    *(ushort4*)(xp + i4) = make_ushort4(f2b(v.x), f2b(v.y), f2b(v.z), f2b(v.w));
}

// W fp32 -> bf16, chunk-major blob [c][256 filters][4 slots][8], zero-padded past K,
// bank-swizzle PRE-APPLIED: slot gs holds logical granule gs ^ ((f>>1)&3)
__global__ __launch_bounds__(256)
void pack_w_kernel(const float* __restrict__ W1, const float* __restrict__ W2,
                   const float* __restrict__ W3, unsigned short* __restrict__ wb)
{
    int G = blockIdx.x * 256 + threadIdx.x;          // 0 .. 116735
    int gs = G & 3;
    int f  = (G >> 2) & 255;
    int c  = G >> 10;                                 // 1024 granules per chunk
    const float* Wg; int K, cb;
    if (c < NCH0)      { Wg = W1; K = 900;  cb = 0; }
    else if (c < NCH1) { Wg = W2; K = 1200; cb = NCH0; }
    else               { Wg = W3; K = 1500; cb = NCH1; }
    int glog = gs ^ ((f >> 1) & 3);
    int kloc = (c - cb) * 32 + glog * 8;
    unsigned short v[8];
#pragma unroll
    for (int j = 0; j < 8; ++j)
        v[j] = (kloc + j < K) ? f2b(Wg[f * K + kloc + j]) : (unsigned short)0;
    unsigned short* dst = wb + (long)G * 8;
    *(ushort4*)dst       = make_ushort4(v[0], v[1], v[2], v[3]);
    *(ushort4*)(dst + 4) = make_ushort4(v[4], v[5], v[6], v[7]);
}

// ---------------- main kernel: X resident in LDS, W streamed ----------------
// 256 blocks (batch x 4 window-tiles of 98), 512 threads (8 waves, wave = 32 filters x 112 windows)

__global__ __launch_bounds__(512, 2)
void convgemm_kernel(const unsigned short* __restrict__ xp,
                     const unsigned short* __restrict__ wb,
                     const float* __restrict__ b1, const float* __restrict__ b2,
                     const float* __restrict__ b3,
                     float* __restrict__ out)
{
    __shared__ unsigned short LDS[XELEM + 4 * WBUF_ELEM];   // 69632B X + 64KB W = 135KB

    const int tid  = threadIdx.x;
    const int lane = tid & 63;
    const int wid  = tid >> 6;
    const int lr   = lane & 15, lg = lane >> 4;
    const int b    = blockIdx.x >> 2;
    const int i0   = (blockIdx.x & 3) * 98;

    // ---- prologue: fill resident X (flat rows i0..i0+115 of batch b, clamped) ----
    const long xstart = ((long)b * SEQ + i0) * EMB;          // 16B-aligned (all i0 mult of 98)
    const long xlim   = (long)64 * SEQ * EMB - 8;
#pragma unroll
    for (int rd = 0; rd < 9; ++rd) {
        int gw = rd * 512 + wid * 64;                        // wave-uniform granule base
        if (gw < XGRAN) {
            long se = xstart + (long)(gw + lane) * 8;
            if (se > xlim) se = xlim;                        // masked-window region only
            gload_lds16(xp + se, &LDS[gw * 8]);
        }
    }
    // ---- stage W chunks 0,1,2 ----
#pragma unroll
    for (int p = 0; p < 3; ++p) {
#pragma unroll
        for (int j = 0; j < 2; ++j) {
            int gw = j * 512 + wid * 64;
            gload_lds16(wb + (long)p * WBUF_ELEM + (long)(gw + lane) * 8,
                        &LDS[XELEM + p * WBUF_ELEM + gw * 8]);
        }
    }
    asm volatile("s_waitcnt vmcnt(6)" ::: "memory");         // X done (8 or 9 fills), W0-2 in flight
    __builtin_amdgcn_sched_barrier(0);
    __builtin_amdgcn_s_barrier();
    __builtin_amdgcn_sched_barrier(0);

    f32x4 acc[2][7];
#pragma unroll
    for (int i = 0; i < 2; ++i)
#pragma unroll
        for (int j = 0; j < 7; ++j)
            acc[i][j] = (f32x4)0.0f;

    const int swzs = (lg ^ ((lr >> 1) & 3)) * 8;             // swizzled W granule slot
    int cend = NCH0, br = 0, bxe = 0;                        // bxe = branch-local k elem offset

    for (int c = 0; c < NCHT; ++c) {
        if (c + 2 < NCHT)      asm volatile("s_waitcnt vmcnt(4)" ::: "memory");
        else if (c + 1 < NCHT) asm volatile("s_waitcnt vmcnt(2)" ::: "memory");
        else                   asm volatile("s_waitcnt vmcnt(0)" ::: "memory");
        __builtin_amdgcn_sched_barrier(0);
        __builtin_amdgcn_s_barrier();                        // chunk c ready; prev reads retired
        __builtin_amdgcn_sched_barrier(0);

        if (c + 3 < NCHT) {                                  // refill retired buffer
            const int bn = (c + 3) & 3;
#pragma unroll
            for (int j = 0; j < 2; ++j) {
                int gw = j * 512 + wid * 64;
                gload_lds16(wb + (long)(c + 3) * WBUF_ELEM + (long)(gw + lane) * 8,
                            &LDS[XELEM + bn * WBUF_ELEM + gw * 8]);
            }
        }

        const unsigned short* Wc = &LDS[XELEM + (c & 3) * WBUF_ELEM];
        short8 af[2];
#pragma unroll
        for (int mi = 0; mi < 2; ++mi)
            af[mi] = *(const short8*)&Wc[(wid * 32 + mi * 16 + lr) * 32 + swzs];

        short8 bx[7];
#pragma unroll
        for (int ni = 0; ni < 7; ++ni) {
            const unsigned short* p = &LDS[(ni * 16 + lr) * EMB + bxe + lg * 8];
            short4v lo = *(const short4v*)p;                 // ds_read_b64 (8B-aligned)
            short4v hi = *(const short4v*)(p + 4);
            bx[ni] = __builtin_shufflevector(lo, hi, 0, 1, 2, 3, 4, 5, 6, 7);
        }

#pragma unroll
        for (int mi = 0; mi < 2; ++mi)
#pragma unroll
            for (int ni = 0; ni < 7; ++ni)
                acc[mi][ni] = __builtin_amdgcn_mfma_f32_16x16x32_bf16(af[mi], bx[ni], acc[mi][ni], 0, 0, 0);

        if (c + 1 == cend) {                                 // branch epilogue (wave-uniform)
            const float* bg = (br == 0) ? b1 : (br == 1) ? b2 : b3;
            const int Nw   = 391 - br;
            const int wlim = min(98, Nw - i0);
            const int obase = b * 768 + br * 256;
#pragma unroll
            for (int mi = 0; mi < 2; ++mi) {
#pragma unroll
                for (int r = 0; r < 4; ++r) {
                    const int d = wid * 32 + mi * 16 + lg * 4 + r;
                    const float bv = bg[d];
                    float m = 0.f;
#pragma unroll
                    for (int ni = 0; ni < 7; ++ni) {
                        int w = ni * 16 + lr;
                        float v = fmaxf(acc[mi][ni][r] + bv, 0.f);
                        if (w >= wlim) v = 0.f;
                        m = fmaxf(m, v);
                    }
#pragma unroll
                    for (int off = 1; off < 16; off <<= 1)
                        m = fmaxf(m, __shfl_xor(m, off));
                    if (lr == 0)
                        atomicMax((int*)(out + obase + d), __float_as_int(m));
                }
            }
#pragma unroll
            for (int i = 0; i < 2; ++i)
#pragma unroll
                for (int j = 0; j < 7; ++j)
                    acc[i][j] = (f32x4)0.0f;
            ++br;
            cend = (br == 1) ? NCH1 : NCHT;
            bxe = -32;                                       // resets to 0 below
        }
        bxe += 32;
        __builtin_amdgcn_sched_barrier(0);
    }
}

// ---------------- fallback (R1 structure) if ws too small ----------------

__device__ __forceinline__ void load_chunk(const float* __restrict__ Wg,
                                           const float* __restrict__ xb,
                                           int K, int dbase, int i0, int k0, int tid,
                                           float4 wv[4], float4 xv[4])
{
#pragma unroll
    for (int i = 0; i < 4; ++i) {
        int fi  = tid + (i << 8);
        int row = fi >> 3;
        int c4  = (fi & 7) << 2;
        int col = k0 + c4;
        if (col < K)
            wv[i] = *(const float4*)(Wg + (long)(dbase + row) * K + col);
        else
            wv[i] = make_float4(0.f, 0.f, 0.f, 0.f);
        int off = (i0 + row) * EMB + col;
        int lim = SEQ * EMB - 4;
        if (off > lim) off = lim;
        xv[i] = *(const float4*)(xb + off);
    }
}

__device__ __forceinline__ void write_chunk(unsigned short (*Wb)[40],
                                            unsigned short (*Xb)[40],
                                            int tid, const float4 wv[4], const float4 xv[4])
{
#pragma unroll
    for (int i = 0; i < 4; ++i) {
        int fi  = tid + (i << 8);
        int row = fi >> 3;
        int c4  = (fi & 7) << 2;
        *(ushort4*)&Wb[row][c4] = make_ushort4(f2b(wv[i].x), f2b(wv[i].y), f2b(wv[i].z), f2b(wv[i].w));
        *(ushort4*)&Xb[row][c4] = make_ushort4(f2b(xv[i].x), f2b(xv[i].y), f2b(xv[i].z), f2b(xv[i].w));
    }
}

__global__ __launch_bounds__(256, 2)
void convmax_fallback(const float* __restrict__ x,
                      const float* __restrict__ W1, const float* __restrict__ W2,
                      const float* __restrict__ W3,
                      const float* __restrict__ b1, const float* __restrict__ b2,
                      const float* __restrict__ b3,
                      float* __restrict__ out)
{
    const int br = blockIdx.z;
    const int K  = (br == 0) ? 900 : (br == 1) ? 1200 : 1500;
    const int Nw = SEQ - 3 - br;
    const float* Wg = (br == 0) ? W1 : (br == 1) ? W2 : W3;
    const float* bg = (br == 0) ? b1 : (br == 1) ? b2 : b3;
    const int b  = blockIdx.x;
    const int mt = blockIdx.y >> 2;
    const int nt = blockIdx.y & 3;
    const int dbase = mt * 128;
    const int i0    = nt * 128;
    const float* xb = x + b * (SEQ * EMB);
    const int nch = (K + 31) >> 5;

    __shared__ unsigned short Wl[2][128][40];
    __shared__ unsigned short Xl[2][128][40];

    const int tid  = threadIdx.x;
    const int lane = tid & 63;
    const int wid  = tid >> 6;
    const int wr = wid >> 1, wc = wid & 1;
    const int lr = lane & 15, lg = lane >> 4;

    f32x4 acc[4][4];
#pragma unroll
    for (int i = 0; i < 4; ++i)
#pragma unroll
        for (int j = 0; j < 4; ++j)
            acc[i][j] = (f32x4)0.0f;

    {
        float4 wv[4], xv[4];
        load_chunk(Wg, xb, K, dbase, i0, 0, tid, wv, xv);
        write_chunk(Wl[0], Xl[0], tid, wv, xv);
    }
    __syncthreads();

    for (int c = 0; c < nch; ++c) {
        const int cur = c & 1;
        float4 wv[4], xv[4];
        const bool pf = (c + 1 < nch);
        if (pf) load_chunk(Wg, xb, K, dbase, i0, (c + 1) << 5, tid, wv, xv);

        short8 af[4], bfr[4];
#pragma unroll
        for (int mi = 0; mi < 4; ++mi)
            af[mi] = *(const short8*)&Wl[cur][wr * 64 + mi * 16 + lr][lg * 8];
#pragma unroll
        for (int ni = 0; ni < 4; ++ni)
            bfr[ni] = *(const short8*)&Xl[cur][wc * 64 + ni * 16 + lr][lg * 8];
#pragma unroll
        for (int mi = 0; mi < 4; ++mi)
#pragma unroll
            for (int ni = 0; ni < 4; ++ni)
                acc[mi][ni] = __builtin_amdgcn_mfma_f32_16x16x32_bf16(af[mi], bfr[ni], acc[mi][ni], 0, 0, 0);

        if (pf) write_chunk(Wl[cur ^ 1], Xl[cur ^ 1], tid, wv, xv);
        __syncthreads();
    }

    const int ob = b * 768 + br * 256;
#pragma unroll
    for (int mi = 0; mi < 4; ++mi) {
#pragma unroll
        for (int rI = 0; rI < 4; ++rI) {
            const int d = dbase + wr * 64 + mi * 16 + lg * 4 + rI;
            const float bv = bg[d];
            float m = 0.f;
#pragma unroll
            for (int ni = 0; ni < 4; ++ni) {
                int win = i0 + wc * 64 + ni * 16 + lr;
                float v = acc[mi][ni][rI] + bv;
                v = fmaxf(v, 0.f);
                if (win >= Nw) v = 0.f;
                m = fmaxf(m, v);
            }
#pragma unroll
            for (int off = 1; off < 16; off <<= 1)
                m = fmaxf(m, __shfl_xor(m, off));
            if (lr == 0)
                atomicMax((int*)(out + ob + d), __float_as_int(m));
        }
    }
}

// ---------------- launch ----------------

extern "C" void kernel_launch(void* const* d_in, const int* in_sizes, int n_in,
                              void* d_out, int out_size, void* d_ws, size_t ws_size,
                              hipStream_t stream) {
    const float* x  = (const float*)d_in[0];
    const float* W1 = (const float*)d_in[1];
    const float* W2 = (const float*)d_in[2];
    const float* W3 = (const float*)d_in[3];
    const float* b1 = (const float*)d_in[4];
    const float* b2 = (const float*)d_in[5];
    const float* b3 = (const float*)d_in[6];
    float* out = (float*)d_out;

    hipMemsetAsync(d_out, 0, (size_t)out_size * sizeof(float), stream);

    const long XTOT = (long)64 * SEQ * EMB;                  // 7,564,800 elems
    const long WBTOT = (long)NCHT * WBUF_ELEM;               // 933,888 elems
    const size_t need = (size_t)(XTOT + WBTOT) * 2;          // ~17 MB

    if (ws_size >= need) {
        unsigned short* xp = (unsigned short*)d_ws;
        unsigned short* wbb = xp + XTOT;

        pack_x_kernel<<<(int)((XTOT / 4 + 255) / 256), 256, 0, stream>>>(x, xp);
        pack_w_kernel<<<456, 256, 0, stream>>>(W1, W2, W3, wbb);
        convgemm_kernel<<<256, 512, 0, stream>>>(xp, wbb, b1, b2, b3, out);
    } else {
        dim3 grid(64, 8, 3);
        convmax_fallback<<<grid, 256, 0, stream>>>(x, W1, W2, W3, b1, b2, b3, out);
    }
}